// Round 10
// baseline (41328.503 us; speedup 1.0000x reference)
//
#include <hip/hip_runtime.h>
#include <hip/hip_bf16.h>

#define Bdim 8192
#define Ddim 1024
#define Hdim 4096
#define NPOW 10
#define TAUZ 1e-5   // hedge band: |z| < TAUZ gets relu'-weight 0.5

// Scaled-fp16-split: split arrays store SCL*value as (hi,lo) fp16.
#define SCL   512.0f
#define ISCL  (1.0f / 512.0f)
#define ISCL2 (1.0f / (512.0f * 512.0f))

typedef _Float16 f16x8 __attribute__((ext_vector_type(8)));
typedef float f32x4 __attribute__((ext_vector_type(4)));

__device__ __forceinline__ float h2f(unsigned short b) {
  _Float16 h = __builtin_bit_cast(_Float16, b);
  return (float)h;
}
__device__ __forceinline__ unsigned short f2h(float v) {
  return __builtin_bit_cast(unsigned short, (_Float16)v);
}
__device__ __forceinline__ void splitf(float v, unsigned short& hi, unsigned short& lo) {
  const float s = v * SCL;
  const _Float16 h = (_Float16)s;
  const _Float16 l = (_Float16)(s - (float)h);
  hi = __builtin_bit_cast(unsigned short, h);
  lo = __builtin_bit_cast(unsigned short, l);
}

__device__ __forceinline__ void gload_lds16(const void* g, void* l) {
  __builtin_amdgcn_global_load_lds(
      (const __attribute__((address_space(1))) void*)g,
      (__attribute__((address_space(3))) void*)l, 16, 0, 0);
}

// ---------------------------------------------------------------------------
// npz1: z1[b,j] = fp64( sum_k x[b,k]*W1[j,k] ) + b1[j]
// -> relu' weight w1 in {0, 0.5, 1} (fp16), h1 = relu(z1) stored fp64.
// ---------------------------------------------------------------------------
#define BT1 32
__global__ __launch_bounds__(256, 1)
void npz1(const float* __restrict__ xc, const float* __restrict__ W1,
          const float* __restrict__ b1,
          unsigned short* __restrict__ w1, double* __restrict__ h1f64)
{
  __shared__ float xs[BT1][Ddim];  // 128 KiB
  const int tid = threadIdx.x;
  const int j   = blockIdx.x * 256 + tid;
  const int b0  = blockIdx.y * BT1;
  for (int idx = tid; idx < BT1 * Ddim / 4; idx += 256)
    ((float4*)&xs[0][0])[idx] = ((const float4*)(xc + (size_t)b0 * Ddim))[idx];
  __syncthreads();

  double acc[BT1];
#pragma unroll
  for (int b = 0; b < BT1; b++) acc[b] = 0.0;
  const float* wr = W1 + (size_t)j * Ddim;
  for (int k = 0; k < Ddim; k += 4) {
    const float4 wv = *(const float4*)(wr + k);
    const double w0 = wv.x, w1d = wv.y, w2 = wv.z, w3 = wv.w;
#pragma unroll
    for (int b = 0; b < BT1; b++) {
      const float4 xv = *(const float4*)(&xs[b][k]);
      double a = acc[b];
      a = fma((double)xv.x, w0, a);
      a = fma((double)xv.y, w1d, a);
      a = fma((double)xv.z, w2, a);
      a = fma((double)xv.w, w3, a);
      acc[b] = a;
    }
  }
  const double bj = (double)b1[j];
#pragma unroll
  for (int b = 0; b < BT1; b++) {
    const double z = acc[b] + bj;
    const float w = (z > TAUZ) ? 1.f : ((z < -TAUZ) ? 0.f : 0.5f);
    const size_t o = (size_t)(b0 + b) * Hdim + j;
    w1[o] = f2h(w);
    h1f64[o] = z > 0.0 ? z : 0.0;
  }
}

// ---------------------------------------------------------------------------
// npz2: z2[b,i] = fp64( sum_k h1[b,k]*W2[i,k] ) + b2[i]
// -> relu' weight w2 in {0, 0.5, 1} (fp16), h2 = relu(z2) stored split-fp16.
// ---------------------------------------------------------------------------
#define BT2 32
#define KC2 512
__global__ __launch_bounds__(256, 1)
void npz2(const double* __restrict__ h1f64, const float* __restrict__ W2,
          const float* __restrict__ b2,
          unsigned short* __restrict__ w2out,
          unsigned short* __restrict__ h2h, unsigned short* __restrict__ h2l)
{
  __shared__ double hs[BT2][KC2];  // 128 KiB
  const int tid = threadIdx.x;
  const int j   = blockIdx.x * 256 + tid;
  const int b0  = blockIdx.y * BT2;

  double acc[BT2];
#pragma unroll
  for (int b = 0; b < BT2; b++) acc[b] = 0.0;
  const float* wr = W2 + (size_t)j * Hdim;

  for (int kc = 0; kc < Hdim; kc += KC2) {
    __syncthreads();
    for (int idx = tid; idx < BT2 * KC2 / 2; idx += 256) {
      const int bb = idx / (KC2 / 2);
      const int kk = (idx % (KC2 / 2)) * 2;
      *(double2*)&hs[bb][kk] =
          *(const double2*)(h1f64 + (size_t)(b0 + bb) * Hdim + kc + kk);
    }
    __syncthreads();
    for (int k = 0; k < KC2; k += 4) {
      const float4 wv = *(const float4*)(wr + kc + k);
      const double w0 = wv.x, w1d = wv.y, w2d = wv.z, w3 = wv.w;
#pragma unroll
      for (int b = 0; b < BT2; b++) {
        double a = acc[b];
        a = fma(hs[b][k + 0], w0, a);
        a = fma(hs[b][k + 1], w1d, a);
        a = fma(hs[b][k + 2], w2d, a);
        a = fma(hs[b][k + 3], w3, a);
        acc[b] = a;
      }
    }
  }
  const double bj = (double)b2[j];
#pragma unroll
  for (int b = 0; b < BT2; b++) {
    const double z = acc[b] + bj;
    const float w = (z > TAUZ) ? 1.f : ((z < -TAUZ) ? 0.f : 0.5f);
    const size_t o = (size_t)(b0 + b) * Hdim + j;
    w2out[o] = f2h(w);
    const float h = z > 0.0 ? (float)z : 0.f;
    unsigned short hh, hl;
    splitf(h, hh, hl);
    h2h[o] = hh;
    h2l[o] = hl;
  }
}

// ---------------------------------------------------------------------------
// y-GEMM: y = h2 @ W3^T + b3 + x.  Split-fp16 3-term MFMA.
// ---------------------------------------------------------------------------
__global__ __launch_bounds__(256, 2)
void gemm_y(const unsigned short* __restrict__ Ah,
            const unsigned short* __restrict__ Al,
            const unsigned short* __restrict__ Bh,
            const unsigned short* __restrict__ Bl,
            int M, int N, int K,
            const float* __restrict__ bias,
            const float* __restrict__ xres,
            float* __restrict__ outF)
{
  __shared__ __align__(16) unsigned short smem[4 * 128 * 32];
  unsigned short* sAh = smem;
  unsigned short* sAl = smem + 4096;
  unsigned short* sBh = smem + 8192;
  unsigned short* sBl = smem + 12288;

  const int t    = threadIdx.x;
  const int bn   = blockIdx.x;
  const int bm   = blockIdx.y;
  const int lane = t & 63;
  const int w    = t >> 6;
  const int wr   = (w >> 1) * 64;
  const int wc   = (w & 1) * 64;
  const int fr   = lane & 15;
  const int kg   = lane >> 4;

  f32x4 acc[4][4];
#pragma unroll
  for (int i = 0; i < 4; i++)
#pragma unroll
    for (int j = 0; j < 4; j++) acc[i][j] = (f32x4){0.f, 0.f, 0.f, 0.f};

  const int sr = t >> 2;
  const int sc = (t & 3) << 3;
  const size_t aRow  = (size_t)(bm * 128 + sr) * K;
  const size_t bRow  = (size_t)(bn * 128 + sr) * K;
  const size_t rowSk = (size_t)64 * K;
  const int ldsOff   = sr * 32 + sc;

  for (int k0 = 0; k0 < K; k0 += 32) {
    __syncthreads();
    {
      const size_t ga = aRow + k0 + sc;
      const size_t gb = bRow + k0 + sc;
      gload_lds16(Ah + ga,         sAh + ldsOff);
      gload_lds16(Ah + ga + rowSk, sAh + 2048 + ldsOff);
      gload_lds16(Al + ga,         sAl + ldsOff);
      gload_lds16(Al + ga + rowSk, sAl + 2048 + ldsOff);
      gload_lds16(Bh + gb,         sBh + ldsOff);
      gload_lds16(Bh + gb + rowSk, sBh + 2048 + ldsOff);
      gload_lds16(Bl + gb,         sBl + ldsOff);
      gload_lds16(Bl + gb + rowSk, sBl + 2048 + ldsOff);
    }
    __syncthreads();

    f16x8 ah[4], al[4], bh[4], bl[4];
#pragma unroll
    for (int i = 0; i < 4; i++) {
      const int ra = (wr + i * 16 + fr) * 32 + kg * 8;
      const int rb = (wc + i * 16 + fr) * 32 + kg * 8;
      ah[i] = *(const f16x8*)(const void*)(sAh + ra);
      al[i] = *(const f16x8*)(const void*)(sAl + ra);
      bh[i] = *(const f16x8*)(const void*)(sBh + rb);
      bl[i] = *(const f16x8*)(const void*)(sBl + rb);
    }
#pragma unroll
    for (int i = 0; i < 4; i++)
#pragma unroll
      for (int j = 0; j < 4; j++) {
        acc[i][j] = __builtin_amdgcn_mfma_f32_16x16x32_f16(ah[i], bh[j], acc[i][j], 0, 0, 0);
        acc[i][j] = __builtin_amdgcn_mfma_f32_16x16x32_f16(ah[i], bl[j], acc[i][j], 0, 0, 0);
        acc[i][j] = __builtin_amdgcn_mfma_f32_16x16x32_f16(al[i], bh[j], acc[i][j], 0, 0, 0);
      }
  }

#pragma unroll
  for (int i = 0; i < 4; i++)
#pragma unroll
    for (int j = 0; j < 4; j++) {
      const int rowb = bm * 128 + wr + i * 16 + kg * 4;
      const int gcol = bn * 128 + wc + j * 16 + fr;
#pragma unroll
      for (int r = 0; r < 4; r++) {
        const size_t o = (size_t)(rowb + r) * N + gcol;
        outF[o] = acc[i][j][r] * ISCL2 + bias[gcol] + xres[o];
      }
    }
}

// ---------------------------------------------------------------------------
// Backward NT GEMM, split-fp16 3-term. A,B split (×SCL).
// EPI 2: v = C*ISCL2 * weight[o] (weight in {0,0.5,1}); store split(v)
// EPI 3: v = C*ISCL2; store split(v)
// ---------------------------------------------------------------------------
template<int EPI>
__global__ __launch_bounds__(256, 2)
void gemm_bwd(const unsigned short* __restrict__ Ah,
              const unsigned short* __restrict__ Al,
              const unsigned short* __restrict__ Bh,
              const unsigned short* __restrict__ Bl,
              int M, int N, int K,
              const unsigned short* __restrict__ wIn,
              unsigned short* __restrict__ outH,
              unsigned short* __restrict__ outL)
{
  __shared__ __align__(16) unsigned short smem[4 * 128 * 32];
  unsigned short* sAh = smem;
  unsigned short* sAl = smem + 4096;
  unsigned short* sBh = smem + 8192;
  unsigned short* sBl = smem + 12288;

  const int t    = threadIdx.x;
  const int bn   = blockIdx.x;
  const int bm   = blockIdx.y;
  const int lane = t & 63;
  const int w    = t >> 6;
  const int wr   = (w >> 1) * 64;
  const int wc   = (w & 1) * 64;
  const int fr   = lane & 15;
  const int kg   = lane >> 4;

  f32x4 acc[4][4];
#pragma unroll
  for (int i = 0; i < 4; i++)
#pragma unroll
    for (int j = 0; j < 4; j++) acc[i][j] = (f32x4){0.f, 0.f, 0.f, 0.f};

  const int sr = t >> 2;
  const int sc = (t & 3) << 3;
  const size_t aRow  = (size_t)(bm * 128 + sr) * K;
  const size_t bRow  = (size_t)(bn * 128 + sr) * K;
  const size_t rowSk = (size_t)64 * K;
  const int ldsOff   = sr * 32 + sc;

  for (int k0 = 0; k0 < K; k0 += 32) {
    __syncthreads();
    {
      const size_t ga = aRow + k0 + sc;
      const size_t gb = bRow + k0 + sc;
      gload_lds16(Ah + ga,         sAh + ldsOff);
      gload_lds16(Ah + ga + rowSk, sAh + 2048 + ldsOff);
      gload_lds16(Al + ga,         sAl + ldsOff);
      gload_lds16(Al + ga + rowSk, sAl + 2048 + ldsOff);
      gload_lds16(Bh + gb,         sBh + ldsOff);
      gload_lds16(Bh + gb + rowSk, sBh + 2048 + ldsOff);
      gload_lds16(Bl + gb,         sBl + ldsOff);
      gload_lds16(Bl + gb + rowSk, sBl + 2048 + ldsOff);
    }
    __syncthreads();

    f16x8 ah[4], al[4], bh[4], bl[4];
#pragma unroll
    for (int i = 0; i < 4; i++) {
      const int ra = (wr + i * 16 + fr) * 32 + kg * 8;
      const int rb = (wc + i * 16 + fr) * 32 + kg * 8;
      ah[i] = *(const f16x8*)(const void*)(sAh + ra);
      al[i] = *(const f16x8*)(const void*)(sAl + ra);
      bh[i] = *(const f16x8*)(const void*)(sBh + rb);
      bl[i] = *(const f16x8*)(const void*)(sBl + rb);
    }
#pragma unroll
    for (int i = 0; i < 4; i++)
#pragma unroll
      for (int j = 0; j < 4; j++) {
        acc[i][j] = __builtin_amdgcn_mfma_f32_16x16x32_f16(ah[i], bh[j], acc[i][j], 0, 0, 0);
        acc[i][j] = __builtin_amdgcn_mfma_f32_16x16x32_f16(ah[i], bl[j], acc[i][j], 0, 0, 0);
        acc[i][j] = __builtin_amdgcn_mfma_f32_16x16x32_f16(al[i], bh[j], acc[i][j], 0, 0, 0);
      }
  }

#pragma unroll
  for (int i = 0; i < 4; i++)
#pragma unroll
    for (int j = 0; j < 4; j++) {
      const int rowb = bm * 128 + wr + i * 16 + kg * 4;
      const int gcol = bn * 128 + wc + j * 16 + fr;
#pragma unroll
      for (int r = 0; r < 4; r++) {
        const size_t o = (size_t)(rowb + r) * N + gcol;
        float v = acc[i][j][r] * ISCL2;
        if (EPI == 2) v *= h2f(wIn[o]);
        unsigned short hh, hl;
        splitf(v, hh, hl);
        outH[o] = hh;
        outL[o] = hl;
      }
    }
}

// ---------------------------------------------------------------------------
// W [R,C] fp32 -> optional Wh/Wl [R,C] (×SCL) and WTh/WTl [C,R] (×SCL)
// ---------------------------------------------------------------------------
__global__ void split_transpose(const float* __restrict__ W, int R, int C,
                                unsigned short* __restrict__ Wh,
                                unsigned short* __restrict__ Wl,
                                unsigned short* __restrict__ WTh,
                                unsigned short* __restrict__ WTl)
{
  __shared__ float tile[32][33];
  const int tx = threadIdx.x, ty = threadIdx.y;
  const int bx = blockIdx.x << 5, by = blockIdx.y << 5;
#pragma unroll
  for (int k = 0; k < 4; k++) {
    const int r = by + ty + k * 8;
    const size_t o = (size_t)r * C + bx + tx;
    const float v = W[o];
    tile[ty + k * 8][tx] = v;
    if (Wh) {
      unsigned short h, l;
      splitf(v, h, l);
      Wh[o] = h;
      Wl[o] = l;
    }
  }
  __syncthreads();
#pragma unroll
  for (int k = 0; k < 4; k++) {
    const int c = bx + ty + k * 8;
    const size_t o = (size_t)c * R + by + tx;
    const float v = tile[tx][ty + k * 8];
    unsigned short h, l;
    splitf(v, h, l);
    WTh[o] = h;
    WTl[o] = l;
  }
}

// fp32 -> split fp16 (×SCL)
__global__ void split_only(const float* __restrict__ X, int n4,
                           unsigned short* __restrict__ Xh, unsigned short* __restrict__ Xl)
{
  const int i = blockIdx.x * blockDim.x + threadIdx.x;
  if (i >= n4) return;
  const float4 v = ((const float4*)X)[i];
  ushort4 hv, lv;
  splitf(v.x, hv.x, lv.x);
  splitf(v.y, hv.y, lv.y);
  splitf(v.z, hv.z, lv.z);
  splitf(v.w, hv.w, lv.w);
  ((ushort4*)Xh)[i] = hv;
  ((ushort4*)Xl)[i] = lv;
}

__global__ void zero_tail(float* __restrict__ t)
{
  const int i = blockIdx.x * blockDim.x + threadIdx.x;
  if (i < Bdim) t[i] = 0.f;
}

// logdet[row] += coeffOverScl * dot(SCL*ut, u); one wave per row
__global__ void dot_acc(const unsigned short* __restrict__ uth,
                        const unsigned short* __restrict__ utl,
                        const float* __restrict__ u,
                        float* __restrict__ tail, float coeffOverScl)
{
  typedef unsigned short u16x8 __attribute__((ext_vector_type(8)));
  const int row  = blockIdx.x * 4 + (threadIdx.x >> 6);
  const int lane = threadIdx.x & 63;
  const size_t base = (size_t)row * Ddim + lane * 16;
  const u16x8* ph = (const u16x8*)(uth + base);
  const u16x8* pl = (const u16x8*)(utl + base);
  const float4* pu = (const float4*)(u + base);
  float s = 0.f;
#pragma unroll
  for (int half = 0; half < 2; half++) {
    const u16x8 hv = ph[half];
    const u16x8 lv = pl[half];
#pragma unroll
    for (int q = 0; q < 2; q++) {
      const float4 uv = pu[half * 2 + q];
      s += (h2f(hv[q * 4 + 0]) + h2f(lv[q * 4 + 0])) * uv.x;
      s += (h2f(hv[q * 4 + 1]) + h2f(lv[q * 4 + 1])) * uv.y;
      s += (h2f(hv[q * 4 + 2]) + h2f(lv[q * 4 + 2])) * uv.z;
      s += (h2f(hv[q * 4 + 3]) + h2f(lv[q * 4 + 3])) * uv.w;
    }
  }
#pragma unroll
  for (int o = 32; o > 0; o >>= 1) s += __shfl_down(s, o);
  if (lane == 0) tail[row] += coeffOverScl * s;
}

// ---------------------------------------------------------------------------
extern "C" void kernel_launch(void* const* d_in, const int* in_sizes, int n_in,
                              void* d_out, int out_size, void* d_ws, size_t ws_size,
                              hipStream_t stream)
{
  (void)in_sizes; (void)n_in; (void)out_size;
  const float* x  = (const float*)d_in[0];
  const float* u  = (const float*)d_in[1];
  const float* W1 = (const float*)d_in[2];
  const float* b1 = (const float*)d_in[3];
  const float* W2 = (const float*)d_in[4];
  const float* b2 = (const float*)d_in[5];
  const float* W3 = (const float*)d_in[6];
  const float* b3 = (const float*)d_in[7];
  float* out = (float*)d_out;
  float* outTail = out + (size_t)Bdim * Ddim;

  const size_t HD = (size_t)Hdim * Ddim;
  const size_t HH = (size_t)Hdim * Hdim;

  // persistent: W1T h/l + W2T h/l + W3 h/l + W3T h/l = 112 MB
  const size_t persistent = 6 * (HD * 2) + 2 * (HH * 2) + 64 * 256;
  // per-chunk/row: ut splits 4096 + h1f64 32768 (aliased by dz1 splits)
  //                + h2 splits 16384 + w1/w2 weights 16384 = 69632
  const int cands[5] = {8192, 4096, 2048, 1024, 512};
  int CB = 512;
  for (int i = 0; i < 5; i++) {
    if (persistent + (size_t)cands[i] * 69632 + 8192 <= ws_size) { CB = cands[i]; break; }
  }

  char* ws = (char*)d_ws;
  size_t off = 0;
  auto carve = [&](size_t bytes) {
    void* p = ws + off;
    off += (bytes + 255) & ~(size_t)255;
    return p;
  };

  unsigned short* W1Th = (unsigned short*)carve(HD * 2);
  unsigned short* W1Tl = (unsigned short*)carve(HD * 2);
  unsigned short* W2Th = (unsigned short*)carve(HH * 2);
  unsigned short* W2Tl = (unsigned short*)carve(HH * 2);
  unsigned short* W3h  = (unsigned short*)carve(HD * 2);
  unsigned short* W3l  = (unsigned short*)carve(HD * 2);
  unsigned short* W3Th = (unsigned short*)carve(HD * 2);
  unsigned short* W3Tl = (unsigned short*)carve(HD * 2);

  const size_t CD = (size_t)CB * Ddim;
  const size_t CH = (size_t)CB * Hdim;
  unsigned short* uth   = (unsigned short*)carve(CD * 2);
  unsigned short* utl   = (unsigned short*)carve(CD * 2);
  double*         h1f64 = (double*)carve(CH * 8);
  unsigned short* h2h   = (unsigned short*)carve(CH * 2);  // later dz2 hi
  unsigned short* h2l   = (unsigned short*)carve(CH * 2);  // later dz2 lo
  unsigned short* w1    = (unsigned short*)carve(CH * 2);  // relu' weights {0,.5,1}
  unsigned short* w2    = (unsigned short*)carve(CH * 2);
  // dz1 splits alias h1f64 (free after npz2): CH*4 bytes <= CH*8
  unsigned short* dz1h = (unsigned short*)h1f64;
  unsigned short* dz1l = dz1h + CH;

  split_transpose<<<dim3(Ddim / 32, Hdim / 32), dim3(32, 8), 0, stream>>>(
      W1, Hdim, Ddim, nullptr, nullptr, W1Th, W1Tl);
  split_transpose<<<dim3(Hdim / 32, Hdim / 32), dim3(32, 8), 0, stream>>>(
      W2, Hdim, Hdim, nullptr, nullptr, W2Th, W2Tl);
  split_transpose<<<dim3(Hdim / 32, Ddim / 32), dim3(32, 8), 0, stream>>>(
      W3, Ddim, Hdim, W3h, W3l, W3Th, W3Tl);
  zero_tail<<<Bdim / 256, 256, 0, stream>>>(outTail);

  const float coeff[NPOW] = {1.f, -1.f / 2.f, 1.f / 3.f, -1.f / 4.f, 1.f / 5.f,
                             -1.f / 6.f, 1.f / 7.f, -1.f / 8.f, 1.f / 9.f, -1.f / 10.f};

  const int nChunk = Bdim / CB;
  for (int c = 0; c < nChunk; c++) {
    const size_t cb0 = (size_t)c * CB;
    const float* xc = x + cb0 * Ddim;
    const float* uc = u + cb0 * Ddim;

    // ---- forward: fp64-exact z1/z2; hedged relu' weights; h2 split ----
    npz1<<<dim3(Hdim / 256, CB / BT1), 256, 0, stream>>>(xc, W1, b1, w1, h1f64);
    npz2<<<dim3(Hdim / 256, CB / BT2), 256, 0, stream>>>(h1f64, W2, b2, w2, h2h, h2l);

    // y = x + h2@W3^T + b3
    gemm_y<<<dim3(Ddim / 128, CB / 128), 256, 0, stream>>>(
        h2h, h2l, W3h, W3l, CB, Ddim, Hdim, b3, xc, out + cb0 * Ddim);

    // ut0 = u (split); h1f64 free for dz1 aliasing after npz2/gemm_y
    split_only<<<(int)(CD / 4) / 256, 256, 0, stream>>>(uc, (int)(CD / 4), uth, utl);

    // ---- Neumann series VJP loop (3-term split backward, hedged weights) ----
    for (int n = 0; n < NPOW; n++) {
      gemm_bwd<2><<<dim3(Hdim / 128, CB / 128), 256, 0, stream>>>(
          uth, utl, W3Th, W3Tl, CB, Hdim, Ddim, w2, h2h, h2l);
      gemm_bwd<2><<<dim3(Hdim / 128, CB / 128), 256, 0, stream>>>(
          h2h, h2l, W2Th, W2Tl, CB, Hdim, Hdim, w1, dz1h, dz1l);
      gemm_bwd<3><<<dim3(Ddim / 128, CB / 128), 256, 0, stream>>>(
          dz1h, dz1l, W1Th, W1Tl, CB, Ddim, Hdim, nullptr, uth, utl);
      dot_acc<<<CB / 4, 256, 0, stream>>>(uth, utl, uc, outTail + cb0, coeff[n] * ISCL);
    }
  }
}

// Round 11
// 21331.006 us; speedup vs baseline: 1.9375x; 1.9375x over previous
//
#include <hip/hip_runtime.h>
#include <hip/hip_bf16.h>

#define Bdim 8192
#define Ddim 1024
#define Hdim 4096
#define NPOW 10
#define TAUZ 1e-5   // hedge band: |z| < TAUZ gets relu'-weight 0.5

// Scaled-fp16-split (y-GEMM): split arrays store SCL*value as (hi,lo) fp16.
#define SCL   512.0f
#define ISCL  (1.0f / 512.0f)
#define ISCL2 (1.0f / (512.0f * 512.0f))

typedef _Float16 f16x8 __attribute__((ext_vector_type(8)));
typedef float f32x4 __attribute__((ext_vector_type(4)));

__device__ __forceinline__ float h2f(unsigned short b) {
  _Float16 h = __builtin_bit_cast(_Float16, b);
  return (float)h;
}
__device__ __forceinline__ unsigned short f2h(float v) {
  return __builtin_bit_cast(unsigned short, (_Float16)v);
}
__device__ __forceinline__ void splitf(float v, unsigned short& hi, unsigned short& lo) {
  const float s = v * SCL;
  const _Float16 h = (_Float16)s;
  const _Float16 l = (_Float16)(s - (float)h);
  hi = __builtin_bit_cast(unsigned short, h);
  lo = __builtin_bit_cast(unsigned short, l);
}

__device__ __forceinline__ void gload_lds16(const void* g, void* l) {
  __builtin_amdgcn_global_load_lds(
      (const __attribute__((address_space(1))) void*)g,
      (__attribute__((address_space(3))) void*)l, 16, 0, 0);
}

// ---------------------------------------------------------------------------
// npz1: z1[b,j] = fp64( sum_k x[b,k]*W1[j,k] ) + b1[j]
// -> relu' weight w1 in {0, 0.5, 1} (fp16), h1 = relu(z1) stored fp32.
// BT1=16: 64KB LDS -> 2 blocks/CU.
// ---------------------------------------------------------------------------
#define BT1 16
__global__ __launch_bounds__(256, 2)
void npz1(const float* __restrict__ xc, const float* __restrict__ W1,
          const float* __restrict__ b1,
          unsigned short* __restrict__ w1, float* __restrict__ h1f)
{
  __shared__ float xs[BT1][Ddim];  // 64 KiB
  const int tid = threadIdx.x;
  const int j   = blockIdx.x * 256 + tid;
  const int b0  = blockIdx.y * BT1;
  for (int idx = tid; idx < BT1 * Ddim / 4; idx += 256)
    ((float4*)&xs[0][0])[idx] = ((const float4*)(xc + (size_t)b0 * Ddim))[idx];
  __syncthreads();

  double acc[BT1];
#pragma unroll
  for (int b = 0; b < BT1; b++) acc[b] = 0.0;
  const float* wr = W1 + (size_t)j * Ddim;
  for (int k = 0; k < Ddim; k += 4) {
    const float4 wv = *(const float4*)(wr + k);
    const double w0 = wv.x, w1d = wv.y, w2 = wv.z, w3 = wv.w;
#pragma unroll
    for (int b = 0; b < BT1; b++) {
      const float4 xv = *(const float4*)(&xs[b][k]);
      double a = acc[b];
      a = fma((double)xv.x, w0, a);
      a = fma((double)xv.y, w1d, a);
      a = fma((double)xv.z, w2, a);
      a = fma((double)xv.w, w3, a);
      acc[b] = a;
    }
  }
  const double bj = (double)b1[j];
#pragma unroll
  for (int b = 0; b < BT1; b++) {
    const double z = acc[b] + bj;
    const float w = (z > TAUZ) ? 1.f : ((z < -TAUZ) ? 0.f : 0.5f);
    const size_t o = (size_t)(b0 + b) * Hdim + j;
    w1[o] = f2h(w);
    h1f[o] = z > 0.0 ? (float)z : 0.f;
  }
}

// ---------------------------------------------------------------------------
// npz2: z2[b,i] = fp64( sum_k h1[b,k]*W2[i,k] ) + b2[i]
// h1 global fp32 (error ~5e-8 on z2, 200x under band margin), staged to LDS
// as double. KC2=256 -> 64KB LDS -> 2 blocks/CU.
// -> relu' weight w2 in {0, 0.5, 1} (fp16), h2 = relu(z2) stored split-fp16.
// ---------------------------------------------------------------------------
#define BT2 32
#define KC2 256
__global__ __launch_bounds__(256, 2)
void npz2(const float* __restrict__ h1f, const float* __restrict__ W2,
          const float* __restrict__ b2,
          unsigned short* __restrict__ w2out,
          unsigned short* __restrict__ h2h, unsigned short* __restrict__ h2l)
{
  __shared__ double hs[BT2][KC2];  // 64 KiB
  const int tid = threadIdx.x;
  const int j   = blockIdx.x * 256 + tid;
  const int b0  = blockIdx.y * BT2;

  double acc[BT2];
#pragma unroll
  for (int b = 0; b < BT2; b++) acc[b] = 0.0;
  const float* wr = W2 + (size_t)j * Hdim;

  for (int kc = 0; kc < Hdim; kc += KC2) {
    __syncthreads();
    for (int idx = tid; idx < BT2 * KC2 / 4; idx += 256) {
      const int bb = idx / (KC2 / 4);
      const int kk = (idx % (KC2 / 4)) * 4;
      const float4 hv = *(const float4*)(h1f + (size_t)(b0 + bb) * Hdim + kc + kk);
      hs[bb][kk + 0] = (double)hv.x;
      hs[bb][kk + 1] = (double)hv.y;
      hs[bb][kk + 2] = (double)hv.z;
      hs[bb][kk + 3] = (double)hv.w;
    }
    __syncthreads();
    for (int k = 0; k < KC2; k += 4) {
      const float4 wv = *(const float4*)(wr + kc + k);
      const double w0 = wv.x, w1d = wv.y, w2d = wv.z, w3 = wv.w;
#pragma unroll
      for (int b = 0; b < BT2; b++) {
        double a = acc[b];
        a = fma(hs[b][k + 0], w0, a);
        a = fma(hs[b][k + 1], w1d, a);
        a = fma(hs[b][k + 2], w2d, a);
        a = fma(hs[b][k + 3], w3, a);
        acc[b] = a;
      }
    }
  }
  const double bj = (double)b2[j];
#pragma unroll
  for (int b = 0; b < BT2; b++) {
    const double z = acc[b] + bj;
    const float w = (z > TAUZ) ? 1.f : ((z < -TAUZ) ? 0.f : 0.5f);
    const size_t o = (size_t)(b0 + b) * Hdim + j;
    w2out[o] = f2h(w);
    const float h = z > 0.0 ? (float)z : 0.f;
    unsigned short hh, hl;
    splitf(h, hh, hl);
    h2h[o] = hh;
    h2l[o] = hl;
  }
}

// ---------------------------------------------------------------------------
// y-GEMM: y = h2 @ W3^T + b3 + x.  Split-fp16 3-term MFMA (m97 structure).
// ---------------------------------------------------------------------------
__global__ __launch_bounds__(256, 2)
void gemm_y(const unsigned short* __restrict__ Ah,
            const unsigned short* __restrict__ Al,
            const unsigned short* __restrict__ Bh,
            const unsigned short* __restrict__ Bl,
            int M, int N, int K,
            const float* __restrict__ bias,
            const float* __restrict__ xres,
            float* __restrict__ outF)
{
  __shared__ __align__(16) unsigned short smem[4 * 128 * 32];
  unsigned short* sAh = smem;
  unsigned short* sAl = smem + 4096;
  unsigned short* sBh = smem + 8192;
  unsigned short* sBl = smem + 12288;

  const int t    = threadIdx.x;
  const int bn   = blockIdx.x;
  const int bm   = blockIdx.y;
  const int lane = t & 63;
  const int w    = t >> 6;
  const int wr   = (w >> 1) * 64;
  const int wc   = (w & 1) * 64;
  const int fr   = lane & 15;
  const int kg   = lane >> 4;

  f32x4 acc[4][4];
#pragma unroll
  for (int i = 0; i < 4; i++)
#pragma unroll
    for (int j = 0; j < 4; j++) acc[i][j] = (f32x4){0.f, 0.f, 0.f, 0.f};

  const int sr = t >> 2;
  const int sc = (t & 3) << 3;
  const size_t aRow  = (size_t)(bm * 128 + sr) * K;
  const size_t bRow  = (size_t)(bn * 128 + sr) * K;
  const size_t rowSk = (size_t)64 * K;
  const int ldsOff   = sr * 32 + sc;

  for (int k0 = 0; k0 < K; k0 += 32) {
    __syncthreads();
    {
      const size_t ga = aRow + k0 + sc;
      const size_t gb = bRow + k0 + sc;
      gload_lds16(Ah + ga,         sAh + ldsOff);
      gload_lds16(Ah + ga + rowSk, sAh + 2048 + ldsOff);
      gload_lds16(Al + ga,         sAl + ldsOff);
      gload_lds16(Al + ga + rowSk, sAl + 2048 + ldsOff);
      gload_lds16(Bh + gb,         sBh + ldsOff);
      gload_lds16(Bh + gb + rowSk, sBh + 2048 + ldsOff);
      gload_lds16(Bl + gb,         sBl + ldsOff);
      gload_lds16(Bl + gb + rowSk, sBl + 2048 + ldsOff);
    }
    __syncthreads();

    f16x8 ah[4], al[4], bh[4], bl[4];
#pragma unroll
    for (int i = 0; i < 4; i++) {
      const int ra = (wr + i * 16 + fr) * 32 + kg * 8;
      const int rb = (wc + i * 16 + fr) * 32 + kg * 8;
      ah[i] = *(const f16x8*)(const void*)(sAh + ra);
      al[i] = *(const f16x8*)(const void*)(sAl + ra);
      bh[i] = *(const f16x8*)(const void*)(sBh + rb);
      bl[i] = *(const f16x8*)(const void*)(sBl + rb);
    }
#pragma unroll
    for (int i = 0; i < 4; i++)
#pragma unroll
      for (int j = 0; j < 4; j++) {
        acc[i][j] = __builtin_amdgcn_mfma_f32_16x16x32_f16(ah[i], bh[j], acc[i][j], 0, 0, 0);
        acc[i][j] = __builtin_amdgcn_mfma_f32_16x16x32_f16(ah[i], bl[j], acc[i][j], 0, 0, 0);
        acc[i][j] = __builtin_amdgcn_mfma_f32_16x16x32_f16(al[i], bh[j], acc[i][j], 0, 0, 0);
      }
  }

#pragma unroll
  for (int i = 0; i < 4; i++)
#pragma unroll
    for (int j = 0; j < 4; j++) {
      const int rowb = bm * 128 + wr + i * 16 + kg * 4;
      const int gcol = bn * 128 + wc + j * 16 + fr;
#pragma unroll
      for (int r = 0; r < 4; r++) {
        const size_t o = (size_t)(rowb + r) * N + gcol;
        outF[o] = acc[i][j][r] * ISCL2 + bias[gcol] + xres[o];
      }
    }
}

// ---------------------------------------------------------------------------
// Backward NT GEMM, single fp16 term (r6-vs-r8 delta: 0.016 absolute — noise).
// A [M,K] fp16 unscaled; B [N,K] = WT hi (×SCL) -> acc = SCL*true.
// EPI 2: v = C*ISCL * weight[o] (weight in {0,0.5,1}); store fp16
// EPI 3: v = C*ISCL; store fp16
// ---------------------------------------------------------------------------
template<int EPI>
__global__ __launch_bounds__(256, 2)
void gemm_b1(const unsigned short* __restrict__ A,
             const unsigned short* __restrict__ B,
             int M, int N, int K,
             const unsigned short* __restrict__ wIn,
             unsigned short* __restrict__ outX)
{
  __shared__ __align__(16) unsigned short smem[2 * 128 * 32];
  unsigned short* sA = smem;
  unsigned short* sB = smem + 4096;

  const int t    = threadIdx.x;
  const int bn   = blockIdx.x;
  const int bm   = blockIdx.y;
  const int lane = t & 63;
  const int w    = t >> 6;
  const int wr   = (w >> 1) * 64;
  const int wc   = (w & 1) * 64;
  const int fr   = lane & 15;
  const int kg   = lane >> 4;

  f32x4 acc[4][4];
#pragma unroll
  for (int i = 0; i < 4; i++)
#pragma unroll
    for (int j = 0; j < 4; j++) acc[i][j] = (f32x4){0.f, 0.f, 0.f, 0.f};

  const int sr = t >> 2;
  const int sc = (t & 3) << 3;
  const size_t aRow  = (size_t)(bm * 128 + sr) * K;
  const size_t bRow  = (size_t)(bn * 128 + sr) * K;
  const size_t rowSk = (size_t)64 * K;
  const int ldsOff   = sr * 32 + sc;

  for (int k0 = 0; k0 < K; k0 += 32) {
    __syncthreads();
    {
      const size_t ga = aRow + k0 + sc;
      const size_t gb = bRow + k0 + sc;
      gload_lds16(A + ga,         sA + ldsOff);
      gload_lds16(A + ga + rowSk, sA + 2048 + ldsOff);
      gload_lds16(B + gb,         sB + ldsOff);
      gload_lds16(B + gb + rowSk, sB + 2048 + ldsOff);
    }
    __syncthreads();

    f16x8 a[4], b[4];
#pragma unroll
    for (int i = 0; i < 4; i++) {
      a[i] = *(const f16x8*)(const void*)(sA + (wr + i * 16 + fr) * 32 + kg * 8);
      b[i] = *(const f16x8*)(const void*)(sB + (wc + i * 16 + fr) * 32 + kg * 8);
    }
#pragma unroll
    for (int i = 0; i < 4; i++)
#pragma unroll
      for (int j = 0; j < 4; j++)
        acc[i][j] = __builtin_amdgcn_mfma_f32_16x16x32_f16(a[i], b[j], acc[i][j], 0, 0, 0);
  }

#pragma unroll
  for (int i = 0; i < 4; i++)
#pragma unroll
    for (int j = 0; j < 4; j++) {
      const int rowb = bm * 128 + wr + i * 16 + kg * 4;
      const int gcol = bn * 128 + wc + j * 16 + fr;
#pragma unroll
      for (int r = 0; r < 4; r++) {
        const size_t o = (size_t)(rowb + r) * N + gcol;
        float v = acc[i][j][r] * ISCL;
        if (EPI == 2) v *= h2f(wIn[o]);
        outX[o] = f2h(v);
      }
    }
}

// ---------------------------------------------------------------------------
// W [R,C] fp32 -> optional Wh/Wl [R,C] (×SCL), WTh [C,R] (×SCL), optional WTl
// ---------------------------------------------------------------------------
__global__ void split_transpose(const float* __restrict__ W, int R, int C,
                                unsigned short* __restrict__ Wh,
                                unsigned short* __restrict__ Wl,
                                unsigned short* __restrict__ WTh,
                                unsigned short* __restrict__ WTl)
{
  __shared__ float tile[32][33];
  const int tx = threadIdx.x, ty = threadIdx.y;
  const int bx = blockIdx.x << 5, by = blockIdx.y << 5;
#pragma unroll
  for (int k = 0; k < 4; k++) {
    const int r = by + ty + k * 8;
    const size_t o = (size_t)r * C + bx + tx;
    const float v = W[o];
    tile[ty + k * 8][tx] = v;
    if (Wh) {
      unsigned short h, l;
      splitf(v, h, l);
      Wh[o] = h;
      Wl[o] = l;
    }
  }
  __syncthreads();
#pragma unroll
  for (int k = 0; k < 4; k++) {
    const int c = bx + ty + k * 8;
    const size_t o = (size_t)c * R + by + tx;
    const float v = tile[tx][ty + k * 8];
    unsigned short h, l;
    splitf(v, h, l);
    WTh[o] = h;
    if (WTl) WTl[o] = l;
  }
}

// fp32 -> plain fp16
__global__ void tofp16(const float* __restrict__ X, int n4,
                       unsigned short* __restrict__ Y)
{
  const int i = blockIdx.x * blockDim.x + threadIdx.x;
  if (i >= n4) return;
  const float4 v = ((const float4*)X)[i];
  ushort4 y;
  y.x = f2h(v.x); y.y = f2h(v.y); y.z = f2h(v.z); y.w = f2h(v.w);
  ((ushort4*)Y)[i] = y;
}

__global__ void zero_tail(float* __restrict__ t)
{
  const int i = blockIdx.x * blockDim.x + threadIdx.x;
  if (i < Bdim) t[i] = 0.f;
}

// logdet[row] += coeff * dot(ut, u) over D=1024; one wave per row
__global__ void dot_acc(const unsigned short* __restrict__ ut,
                        const float* __restrict__ u,
                        float* __restrict__ tail, float coeff)
{
  typedef unsigned short u16x8 __attribute__((ext_vector_type(8)));
  const int row  = blockIdx.x * 4 + (threadIdx.x >> 6);
  const int lane = threadIdx.x & 63;
  const size_t base = (size_t)row * Ddim + lane * 16;
  const u16x8* ph = (const u16x8*)(ut + base);
  const float4* pu = (const float4*)(u + base);
  float s = 0.f;
#pragma unroll
  for (int half = 0; half < 2; half++) {
    const u16x8 hv = ph[half];
#pragma unroll
    for (int q = 0; q < 2; q++) {
      const float4 uv = pu[half * 2 + q];
      s += h2f(hv[q * 4 + 0]) * uv.x;
      s += h2f(hv[q * 4 + 1]) * uv.y;
      s += h2f(hv[q * 4 + 2]) * uv.z;
      s += h2f(hv[q * 4 + 3]) * uv.w;
    }
  }
#pragma unroll
  for (int o = 32; o > 0; o >>= 1) s += __shfl_down(s, o);
  if (lane == 0) tail[row] += coeff * s;
}

// ---------------------------------------------------------------------------
extern "C" void kernel_launch(void* const* d_in, const int* in_sizes, int n_in,
                              void* d_out, int out_size, void* d_ws, size_t ws_size,
                              hipStream_t stream)
{
  (void)in_sizes; (void)n_in; (void)out_size;
  const float* x  = (const float*)d_in[0];
  const float* u  = (const float*)d_in[1];
  const float* W1 = (const float*)d_in[2];
  const float* b1 = (const float*)d_in[3];
  const float* W2 = (const float*)d_in[4];
  const float* b2 = (const float*)d_in[5];
  const float* W3 = (const float*)d_in[6];
  const float* b3 = (const float*)d_in[7];
  float* out = (float*)d_out;
  float* outTail = out + (size_t)Bdim * Ddim;

  const size_t HD = (size_t)Hdim * Ddim;
  const size_t HH = (size_t)Hdim * Hdim;

  // persistent: W1Th(8) + W2Th(32) + W3h/W3l/W3Th(24) = 64 MB
  const size_t persistent = 4 * (HD * 2) + (HH * 2) + 64 * 256;
  // per-row: ut 2048 + h1f 16384 (aliased by dz2+dz1 fp16) + h2 splits 16384
  //          + w1/w2 16384 = 51200
  const int cands[5] = {8192, 4096, 2048, 1024, 512};
  int CB = 512;
  for (int i = 0; i < 5; i++) {
    if (persistent + (size_t)cands[i] * 51200 + 8192 <= ws_size) { CB = cands[i]; break; }
  }

  char* ws = (char*)d_ws;
  size_t off = 0;
  auto carve = [&](size_t bytes) {
    void* p = ws + off;
    off += (bytes + 255) & ~(size_t)255;
    return p;
  };

  unsigned short* W1Th = (unsigned short*)carve(HD * 2);
  unsigned short* W2Th = (unsigned short*)carve(HH * 2);
  unsigned short* W3h  = (unsigned short*)carve(HD * 2);
  unsigned short* W3l  = (unsigned short*)carve(HD * 2);
  unsigned short* W3Th = (unsigned short*)carve(HD * 2);

  const size_t CD = (size_t)CB * Ddim;
  const size_t CH = (size_t)CB * Hdim;
  unsigned short* ut  = (unsigned short*)carve(CD * 2);
  float*          h1f = (float*)carve(CH * 4);
  unsigned short* h2h = (unsigned short*)carve(CH * 2);
  unsigned short* h2l = (unsigned short*)carve(CH * 2);
  unsigned short* w1  = (unsigned short*)carve(CH * 2);  // relu' weights {0,.5,1}
  unsigned short* w2  = (unsigned short*)carve(CH * 2);
  // dz2/dz1 (fp16) alias h1f (free after npz2): 2×CH×2 = CH×4 exact fit
  unsigned short* dz2 = (unsigned short*)h1f;
  unsigned short* dz1 = dz2 + CH;

  split_transpose<<<dim3(Ddim / 32, Hdim / 32), dim3(32, 8), 0, stream>>>(
      W1, Hdim, Ddim, nullptr, nullptr, W1Th, nullptr);
  split_transpose<<<dim3(Hdim / 32, Hdim / 32), dim3(32, 8), 0, stream>>>(
      W2, Hdim, Hdim, nullptr, nullptr, W2Th, nullptr);
  split_transpose<<<dim3(Hdim / 32, Ddim / 32), dim3(32, 8), 0, stream>>>(
      W3, Ddim, Hdim, W3h, W3l, W3Th, nullptr);
  zero_tail<<<Bdim / 256, 256, 0, stream>>>(outTail);

  const float coeff[NPOW] = {1.f, -1.f / 2.f, 1.f / 3.f, -1.f / 4.f, 1.f / 5.f,
                             -1.f / 6.f, 1.f / 7.f, -1.f / 8.f, 1.f / 9.f, -1.f / 10.f};

  const int nChunk = Bdim / CB;
  for (int c = 0; c < nChunk; c++) {
    const size_t cb0 = (size_t)c * CB;
    const float* xc = x + cb0 * Ddim;
    const float* uc = u + cb0 * Ddim;

    // ---- forward: fp64-exact z1/z2; hedged relu' weights; h1 fp32, h2 split ----
    npz1<<<dim3(Hdim / 256, CB / BT1), 256, 0, stream>>>(xc, W1, b1, w1, h1f);
    npz2<<<dim3(Hdim / 256, CB / BT2), 256, 0, stream>>>(h1f, W2, b2, w2, h2h, h2l);

    // y = x + h2@W3^T + b3
    gemm_y<<<dim3(Ddim / 128, CB / 128), 256, 0, stream>>>(
        h2h, h2l, W3h, W3l, CB, Ddim, Hdim, b3, xc, out + cb0 * Ddim);

    // ut0 = u (fp16); h1f free for dz aliasing after npz2
    tofp16<<<(int)(CD / 4) / 256, 256, 0, stream>>>(uc, (int)(CD / 4), ut);

    // ---- Neumann series VJP loop (1-term fp16, hedged weights) ----
    for (int n = 0; n < NPOW; n++) {
      gemm_b1<2><<<dim3(Hdim / 128, CB / 128), 256, 0, stream>>>(
          ut, W3Th, CB, Hdim, Ddim, w2, dz2);
      gemm_b1<2><<<dim3(Hdim / 128, CB / 128), 256, 0, stream>>>(
          dz2, W2Th, CB, Hdim, Hdim, w1, dz1);
      gemm_b1<3><<<dim3(Ddim / 128, CB / 128), 256, 0, stream>>>(
          dz1, W1Th, CB, Ddim, Hdim, nullptr, ut);
      dot_acc<<<CB / 4, 256, 0, stream>>>(ut, uc, outTail + cb0, coeff[n]);
    }
  }
}